// Round 1
// baseline (322.774 us; speedup 1.0000x reference)
//
#include <hip/hip_runtime.h>
#include <stdint.h>

#define BATCH 64
#define F_ENC 2048
#define HID 8192
#define NCLS 100
#define NMAT 6

typedef unsigned long long ull;

// ---------------------------------------------------------------------------
// Kernel 1: binarize x and transpose-pack into per-column 64-bit batch masks.
// Also zeroes d_out (so the logits kernel can atomicAdd into it).
// ---------------------------------------------------------------------------
__global__ void pack_kernel(const float* __restrict__ x, ull* __restrict__ A0,
                            float* __restrict__ out) {
  int c = blockIdx.x * blockDim.x + threadIdx.x;  // 2048 threads total
  for (int i = c; i < BATCH * NCLS; i += F_ENC) out[i] = 0.f;
  if (c < F_ENC) {
    ull m = 0;
    for (int b = 0; b < BATCH; ++b)
      m |= (ull)(x[(size_t)b * F_ENC + c] > 0.5f) << b;
    A0[c] = m;
  }
}

// ---------------------------------------------------------------------------
// Kernel 2: stream every W matrix (the 1.152 GB read) and extract the <=8
// nonzero (col, sign) entries per neuron row. One block per row.
// Entry format: uint16 = col (13 bits) | sign<<15.  0xFFFF = empty sentinel.
// ---------------------------------------------------------------------------
__global__ void __launch_bounds__(256) sparsify_kernel(
    const uint32_t* __restrict__ W0a, const uint32_t* __restrict__ W0b,
    const uint32_t* __restrict__ W1a, const uint32_t* __restrict__ W1b,
    const uint32_t* __restrict__ W2a, const uint32_t* __restrict__ W2b,
    uint16_t* __restrict__ entries) {
  int m = blockIdx.x >> 13;          // which matrix (0..5)
  int r = blockIdx.x & (HID - 1);    // row within matrix
  const uint32_t* Wbase;
  switch (m) {
    case 0: Wbase = W0a; break;
    case 1: Wbase = W0b; break;
    case 2: Wbase = W1a; break;
    case 3: Wbase = W1b; break;
    case 4: Wbase = W2a; break;
    default: Wbase = W2b; break;
  }
  const int cols = (m < 2) ? F_ENC : HID;
  const uint4* row = (const uint4*)(Wbase + (size_t)r * cols);
  const int nvec = cols >> 2;

  __shared__ unsigned int s_cnt;
  __shared__ uint16_t s_ent[8];
  if (threadIdx.x == 0) s_cnt = 0u;
  __syncthreads();

  for (int i = threadIdx.x; i < nvec; i += 256) {
    uint4 w = row[i];
    if (w.x | w.y | w.z | w.w) {           // rare: <=8 nonzeros per row
      uint32_t vals[4] = {w.x, w.y, w.z, w.w};
#pragma unroll
      for (int e = 0; e < 4; ++e) {
        uint32_t u = vals[e];
        if (u != 0u) {                     // value is exactly +1.0f or -1.0f
          unsigned int slot = atomicAdd(&s_cnt, 1u);
          if (slot < 8u) {
            uint16_t col = (uint16_t)((i << 2) + e);
            s_ent[slot] = (uint16_t)(col | ((u >> 31) << 15));
          }
        }
      }
    }
  }
  __syncthreads();
  if (threadIdx.x < 8) {
    unsigned int cnt = s_cnt;
    uint16_t v = (threadIdx.x < cnt) ? s_ent[threadIdx.x] : (uint16_t)0xFFFF;
    entries[(size_t)blockIdx.x * 8 + threadIdx.x] = v;
  }
}

// ---------------------------------------------------------------------------
// Bit-sliced 4-bit counters over the 64-batch bitmask lanes.
// ---------------------------------------------------------------------------
struct BS4 { ull p0, p1, p2, p3; };

__device__ inline void bs_add(BS4& a, ull m) {
  ull c = m, t;
  t = a.p0 ^ c; c &= a.p0; a.p0 = t;
  t = a.p1 ^ c; c &= a.p1; a.p1 = t;
  t = a.p2 ^ c; c &= a.p2; a.p2 = t;
  a.p3 ^= c;                              // count <= 8, no overflow
}

// fired = (plus >= minus + 4), per batch bit
__device__ inline ull bs_fired(const BS4& A, const BS4& Mn) {
  ull b0 = Mn.p0, b1 = Mn.p1;
  ull carry = Mn.p2;
  ull b2 = ~Mn.p2;
  ull b3 = Mn.p3 ^ carry;
  ull b4 = Mn.p3 & carry;
  ull res = 0, eq = ~0ull;
  eq &= ~b4;                              // a4 == 0
  res |= eq & A.p3 & ~b3; eq &= ~(A.p3 ^ b3);
  res |= eq & A.p2 & ~b2; eq &= ~(A.p2 ^ b2);
  res |= eq & A.p1 & ~b1; eq &= ~(A.p1 ^ b1);
  res |= eq & A.p0 & ~b0; eq &= ~(A.p0 ^ b0);
  return res | eq;
}

__device__ inline ull segment_fired(const uint16_t* __restrict__ ent,
                                    const ull* __restrict__ Aprev) {
  BS4 plus{0, 0, 0, 0}, minus{0, 0, 0, 0};
#pragma unroll
  for (int i = 0; i < 8; ++i) {
    uint16_t e = ent[i];
    if (e == 0xFFFF) break;
    ull M = Aprev[e & 0x1FFF];
    if (e & 0x8000) bs_add(minus, M); else bs_add(plus, M);
  }
  return bs_fired(plus, minus);
}

// ---------------------------------------------------------------------------
// Kernel 3: one layer. thread h: fired = seg0(h) || seg1(h).
// ---------------------------------------------------------------------------
__global__ void layer_kernel(const uint16_t* __restrict__ ent0,
                             const uint16_t* __restrict__ ent1,
                             const ull* __restrict__ Aprev,
                             ull* __restrict__ Anext) {
  int h = blockIdx.x * blockDim.x + threadIdx.x;
  if (h >= HID) return;
  ull f = segment_fired(ent0 + (size_t)h * 8, Aprev)
        | segment_fired(ent1 + (size_t)h * 8, Aprev);
  Anext[h] = f;
}

// ---------------------------------------------------------------------------
// Kernel 4: logits = a1@O0 + a2@O1 + a3@O2.  Block = 128-row h-chunk;
// LDS acc[64][100], thread j owns class column j (no LDS races);
// global atomicAdd into zeroed d_out at the end.
// ---------------------------------------------------------------------------
__global__ void __launch_bounds__(128) logits_kernel(
    const ull* __restrict__ A1, const ull* __restrict__ A2,
    const ull* __restrict__ A3,
    const float* __restrict__ O0, const float* __restrict__ O1,
    const float* __restrict__ O2, float* __restrict__ out) {
  __shared__ float acc[BATCH * NCLS];     // 25.6 KB
  for (int i = threadIdx.x; i < BATCH * NCLS; i += blockDim.x) acc[i] = 0.f;
  __syncthreads();
  const int j = threadIdx.x;
  const int h0 = blockIdx.x * 128;
  if (j < NCLS) {
    for (int k = 0; k < 128; ++k) {
      int h = h0 + k;
      ull m;
      m = A1[h];
      if (m) {
        float o = O0[(size_t)h * NCLS + j];
        do { int b = __builtin_ctzll(m); m &= m - 1; acc[b * NCLS + j] += o; } while (m);
      }
      m = A2[h];
      if (m) {
        float o = O1[(size_t)h * NCLS + j];
        do { int b = __builtin_ctzll(m); m &= m - 1; acc[b * NCLS + j] += o; } while (m);
      }
      m = A3[h];
      if (m) {
        float o = O2[(size_t)h * NCLS + j];
        do { int b = __builtin_ctzll(m); m &= m - 1; acc[b * NCLS + j] += o; } while (m);
      }
    }
  }
  __syncthreads();
  for (int i = threadIdx.x; i < BATCH * NCLS; i += blockDim.x)
    atomicAdd(&out[i], acc[i]);
}

// ---------------------------------------------------------------------------
extern "C" void kernel_launch(void* const* d_in, const int* in_sizes, int n_in,
                              void* d_out, int out_size, void* d_ws, size_t ws_size,
                              hipStream_t stream) {
  const float*    x   = (const float*)d_in[0];
  const uint32_t* W0a = (const uint32_t*)d_in[1];
  const uint32_t* W0b = (const uint32_t*)d_in[2];
  const uint32_t* W1a = (const uint32_t*)d_in[3];
  const uint32_t* W1b = (const uint32_t*)d_in[4];
  const uint32_t* W2a = (const uint32_t*)d_in[5];
  const uint32_t* W2b = (const uint32_t*)d_in[6];
  const float*    O0  = (const float*)d_in[7];
  const float*    O1  = (const float*)d_in[8];
  const float*    O2  = (const float*)d_in[9];
  float* out = (float*)d_out;
  char*  ws  = (char*)d_ws;

  // ws layout (all written before read every call; ~1 MB total):
  ull* A0 = (ull*)(ws);                          // 2048*8   = 16384 B
  ull* A1 = (ull*)(ws + 16384);                  // 8192*8   = 65536 B
  ull* A2 = (ull*)(ws + 16384 + 65536);
  ull* A3 = (ull*)(ws + 16384 + 2 * 65536);
  uint16_t* entries = (uint16_t*)(ws + 16384 + 3 * 65536);  // 49152*8*2 = 786432 B

  pack_kernel<<<8, 256, 0, stream>>>(x, A0, out);
  sparsify_kernel<<<NMAT * HID, 256, 0, stream>>>(W0a, W0b, W1a, W1b, W2a, W2b,
                                                  entries);
  layer_kernel<<<HID / 256, 256, 0, stream>>>(
      entries + (size_t)0 * HID * 8, entries + (size_t)1 * HID * 8, A0, A1);
  layer_kernel<<<HID / 256, 256, 0, stream>>>(
      entries + (size_t)2 * HID * 8, entries + (size_t)3 * HID * 8, A1, A2);
  layer_kernel<<<HID / 256, 256, 0, stream>>>(
      entries + (size_t)4 * HID * 8, entries + (size_t)5 * HID * 8, A2, A3);
  logits_kernel<<<HID / 128, 128, 0, stream>>>(A1, A2, A3, O0, O1, O2, out);
}

// Round 2
// 299.778 us; speedup vs baseline: 1.0767x; 1.0767x over previous
//
#include <hip/hip_runtime.h>
#include <stdint.h>

#define BATCH 64
#define F_ENC 2048
#define HID 8192
#define NCLS 100
#define NMAT 6

typedef unsigned long long ull;

// ---------------------------------------------------------------------------
// Kernel 1: binarize x and transpose-pack into per-column 64-bit batch masks.
// ---------------------------------------------------------------------------
__global__ void pack_kernel(const float* __restrict__ x, ull* __restrict__ A0) {
  int c = blockIdx.x * blockDim.x + threadIdx.x;  // 2048 threads total
  if (c < F_ENC) {
    ull m = 0;
#pragma unroll
    for (int b = 0; b < BATCH; ++b)
      m |= (ull)(x[(size_t)b * F_ENC + c] > 0.5f) << b;
    A0[c] = m;
  }
}

// ---------------------------------------------------------------------------
// Kernel 2: stream every W matrix (1.21 GB) and extract the <=8 nonzero
// (col, sign) entries per neuron row. One block per row. All of a thread's
// loads are issued before any is consumed -> deep MLP, BW-bound not
// latency-bound. Entry: uint16 = col (13b) | sign<<15. 0xFFFF = empty.
// ---------------------------------------------------------------------------
__device__ __forceinline__ void scan_vec(uint4 w, int vecIdx,
                                         unsigned* s_cnt, uint16_t* s_ent) {
  if (w.x | w.y | w.z | w.w) {  // rare: <=8 nonzeros per whole row
    uint32_t vals[4] = {w.x, w.y, w.z, w.w};
#pragma unroll
    for (int e = 0; e < 4; ++e) {
      uint32_t u = vals[e];
      if (u != 0u) {  // value is exactly +1.0f or -1.0f
        unsigned slot = atomicAdd(s_cnt, 1u);
        s_ent[slot & 15u] =
            (uint16_t)(((vecIdx << 2) + e) | ((u >> 31) << 15));
      }
    }
  }
}

__global__ void __launch_bounds__(256) sparsify_kernel(
    const uint32_t* __restrict__ W0a, const uint32_t* __restrict__ W0b,
    const uint32_t* __restrict__ W1a, const uint32_t* __restrict__ W1b,
    const uint32_t* __restrict__ W2a, const uint32_t* __restrict__ W2b,
    uint16_t* __restrict__ entries) {
  int m = blockIdx.x >> 13;          // which matrix (0..5)
  int r = blockIdx.x & (HID - 1);    // row within matrix
  const uint32_t* Wbase;
  switch (m) {
    case 0: Wbase = W0a; break;
    case 1: Wbase = W0b; break;
    case 2: Wbase = W1a; break;
    case 3: Wbase = W1b; break;
    case 4: Wbase = W2a; break;
    default: Wbase = W2b; break;
  }
  const int cols = (m < 2) ? F_ENC : HID;
  const uint4* row = (const uint4*)(Wbase + (size_t)r * cols);

  __shared__ unsigned s_cnt;
  __shared__ uint16_t s_ent[16];
  if (threadIdx.x == 0) s_cnt = 0u;
  __syncthreads();

  if (cols == F_ENC) {  // 2 x dwordx4 per thread, issued together
    uint4 w0 = row[threadIdx.x];
    uint4 w1 = row[threadIdx.x + 256];
    scan_vec(w0, threadIdx.x, &s_cnt, s_ent);
    scan_vec(w1, threadIdx.x + 256, &s_cnt, s_ent);
  } else {              // 8 x dwordx4 per thread (whole 32KB row in flight)
    uint4 w[8];
#pragma unroll
    for (int e = 0; e < 8; ++e) w[e] = row[threadIdx.x + (e << 8)];
#pragma unroll
    for (int e = 0; e < 8; ++e)
      scan_vec(w[e], threadIdx.x + (e << 8), &s_cnt, s_ent);
  }
  __syncthreads();
  if (threadIdx.x < 8) {
    unsigned cnt = s_cnt;
    uint16_t v = (threadIdx.x < cnt) ? s_ent[threadIdx.x] : (uint16_t)0xFFFF;
    entries[(size_t)blockIdx.x * 8 + threadIdx.x] = v;
  }
}

// ---------------------------------------------------------------------------
// Bit-sliced 4-bit counters over the 64-batch bitmask lanes.
// ---------------------------------------------------------------------------
struct BS4 { ull p0, p1, p2, p3; };

__device__ __forceinline__ void bs_add(BS4& a, ull m) {
  ull c = m, t;
  t = a.p0 ^ c; c &= a.p0; a.p0 = t;
  t = a.p1 ^ c; c &= a.p1; a.p1 = t;
  t = a.p2 ^ c; c &= a.p2; a.p2 = t;
  a.p3 ^= c;  // count <= 8, no overflow
}

// fired = (plus >= minus + 4), per batch bit
__device__ __forceinline__ ull bs_fired(const BS4& A, const BS4& Mn) {
  ull b0 = Mn.p0, b1 = Mn.p1;
  ull carry = Mn.p2;
  ull b2 = ~Mn.p2;
  ull b3 = Mn.p3 ^ carry;
  ull b4 = Mn.p3 & carry;
  ull res = 0, eq = ~0ull;
  eq &= ~b4;  // a4 == 0
  res |= eq & A.p3 & ~b3; eq &= ~(A.p3 ^ b3);
  res |= eq & A.p2 & ~b2; eq &= ~(A.p2 ^ b2);
  res |= eq & A.p1 & ~b1; eq &= ~(A.p1 ^ b1);
  res |= eq & A.p0 & ~b0; eq &= ~(A.p0 ^ b0);
  return res | eq;
}

// ---------------------------------------------------------------------------
// Kernel 3: one layer. Entries loaded as one uint4 per segment; all 16
// Aprev gathers issued in parallel (chain depth 2, was 16).
// ---------------------------------------------------------------------------
__global__ void __launch_bounds__(256) layer_kernel(
    const uint16_t* __restrict__ ent0, const uint16_t* __restrict__ ent1,
    const ull* __restrict__ Aprev, ull* __restrict__ Anext) {
  int h = blockIdx.x * blockDim.x + threadIdx.x;
  if (h >= HID) return;
  uint4 p0 = ((const uint4*)ent0)[h];
  uint4 p1 = ((const uint4*)ent1)[h];
  uint32_t wd[8] = {p0.x, p0.y, p0.z, p0.w, p1.x, p1.y, p1.z, p1.w};
  uint16_t es[16];
#pragma unroll
  for (int i = 0; i < 8; ++i) {
    es[2 * i]     = (uint16_t)(wd[i] & 0xFFFFu);
    es[2 * i + 1] = (uint16_t)(wd[i] >> 16);
  }
  ull M[16];
#pragma unroll
  for (int i = 0; i < 16; ++i) {
    int idx = (es[i] == 0xFFFF) ? 0 : (es[i] & 0x1FFF);
    ull v = Aprev[idx];
    M[i] = (es[i] == 0xFFFF) ? 0ull : v;
  }
  ull f = 0;
#pragma unroll
  for (int s = 0; s < 2; ++s) {
    BS4 P{0, 0, 0, 0}, N{0, 0, 0, 0};
#pragma unroll
    for (int i = 0; i < 8; ++i) {
      uint16_t e = es[s * 8 + i];
      ull Mm = M[s * 8 + i];
      ull mp = (e & 0x8000) ? 0ull : Mm;
      ull mn = (e & 0x8000) ? Mm : 0ull;
      bs_add(P, mp);
      bs_add(N, mn);
    }
    f |= bs_fired(P, N);
  }
  Anext[h] = f;
}

// ---------------------------------------------------------------------------
// Kernel 4a: per-block partial logits into ws (no global atomics).
// Kernel 4b: reduce partials into d_out.
// ---------------------------------------------------------------------------
__global__ void __launch_bounds__(128) logits_partial(
    const ull* __restrict__ A1, const ull* __restrict__ A2,
    const ull* __restrict__ A3,
    const float* __restrict__ O0, const float* __restrict__ O1,
    const float* __restrict__ O2, float* __restrict__ part, int rows) {
  __shared__ float acc[BATCH * NCLS];  // 25.6 KB
  for (int i = threadIdx.x; i < BATCH * NCLS; i += 128) acc[i] = 0.f;
  __syncthreads();
  const int j = threadIdx.x;
  const int h0 = blockIdx.x * rows;
  if (j < NCLS) {
    for (int k = 0; k < rows; ++k) {
      int h = h0 + k;
      ull m;
      m = A1[h];
      if (m) {
        float o = O0[(size_t)h * NCLS + j];
        do { int b = __builtin_ctzll(m); m &= m - 1; acc[b * NCLS + j] += o; } while (m);
      }
      m = A2[h];
      if (m) {
        float o = O1[(size_t)h * NCLS + j];
        do { int b = __builtin_ctzll(m); m &= m - 1; acc[b * NCLS + j] += o; } while (m);
      }
      m = A3[h];
      if (m) {
        float o = O2[(size_t)h * NCLS + j];
        do { int b = __builtin_ctzll(m); m &= m - 1; acc[b * NCLS + j] += o; } while (m);
      }
    }
  }
  __syncthreads();
  float* dst = part + (size_t)blockIdx.x * (BATCH * NCLS);
  for (int i = threadIdx.x; i < BATCH * NCLS; i += 128) dst[i] = acc[i];
}

__global__ void logits_reduce(const float* __restrict__ part,
                              float* __restrict__ out, int nb) {
  int i = blockIdx.x * 256 + threadIdx.x;
  if (i >= BATCH * NCLS) return;
  float s = 0.f;
  for (int b = 0; b < nb; ++b) s += part[(size_t)b * (BATCH * NCLS) + i];
  out[i] = s;
}

// ---------------------------------------------------------------------------
extern "C" void kernel_launch(void* const* d_in, const int* in_sizes, int n_in,
                              void* d_out, int out_size, void* d_ws, size_t ws_size,
                              hipStream_t stream) {
  const float*    x   = (const float*)d_in[0];
  const uint32_t* W0a = (const uint32_t*)d_in[1];
  const uint32_t* W0b = (const uint32_t*)d_in[2];
  const uint32_t* W1a = (const uint32_t*)d_in[3];
  const uint32_t* W1b = (const uint32_t*)d_in[4];
  const uint32_t* W2a = (const uint32_t*)d_in[5];
  const uint32_t* W2b = (const uint32_t*)d_in[6];
  const float*    O0  = (const float*)d_in[7];
  const float*    O1  = (const float*)d_in[8];
  const float*    O2  = (const float*)d_in[9];
  float* out = (float*)d_out;
  char*  ws  = (char*)d_ws;

  // ws layout (all written before read every call):
  ull* A0 = (ull*)(ws);                          // 2048*8   = 16384 B
  ull* A1 = (ull*)(ws + 16384);                  // 8192*8   = 65536 B
  ull* A2 = (ull*)(ws + 16384 + 65536);
  ull* A3 = (ull*)(ws + 16384 + 2 * 65536);
  uint16_t* entries = (uint16_t*)(ws + 16384 + 3 * 65536);  // 786432 B
  size_t base = 16384 + 3 * 65536 + 786432;                 // = 999424
  float* part = (float*)(ws + base);

  // choose #partial blocks by available ws (each needs 25600 B)
  size_t avail = (ws_size > base) ? (ws_size - base) : 0;
  int NB = 128;
  while (NB > 1 && (size_t)NB * (BATCH * NCLS * 4) > avail) NB >>= 1;
  int rows = HID / NB;

  pack_kernel<<<8, 256, 0, stream>>>(x, A0);
  sparsify_kernel<<<NMAT * HID, 256, 0, stream>>>(W0a, W0b, W1a, W1b, W2a, W2b,
                                                  entries);
  layer_kernel<<<HID / 256, 256, 0, stream>>>(
      entries + (size_t)0 * HID * 8, entries + (size_t)1 * HID * 8, A0, A1);
  layer_kernel<<<HID / 256, 256, 0, stream>>>(
      entries + (size_t)2 * HID * 8, entries + (size_t)3 * HID * 8, A1, A2);
  layer_kernel<<<HID / 256, 256, 0, stream>>>(
      entries + (size_t)4 * HID * 8, entries + (size_t)5 * HID * 8, A2, A3);
  logits_partial<<<NB, 128, 0, stream>>>(A1, A2, A3, O0, O1, O2, part, rows);
  logits_reduce<<<(BATCH * NCLS + 255) / 256, 256, 0, stream>>>(part, out, NB);
}